// Round 11
// baseline (143.055 us; speedup 1.0000x reference)
//
#include <hip/hip_runtime.h>
#include <math.h>

#define BB 8
#define NN 576
#define DD 1024
#define KK 64
#define HH 512
#define WW 512
#define OUTD 256
#define HF 24
#define XSTRIDE 1032   // 1029 padded to 1032 (16B-aligned rows)

typedef int iv4 __attribute__((ext_vector_type(4)));

// ---------------- K0: m_small gather + inv_msum (tiny, ~3-4 us) -------------
__global__ __launch_bounds__(576) void k_ms(const int* __restrict__ masks,
                                            float* __restrict__ msbuf,
                                            float* __restrict__ invbuf) {
    int bk = blockIdx.x;           // 512 blocks, one per (b,k)
    int tid = threadIdx.x;         // 576
    const int* mb = masks + (size_t)bk * (HH * WW);
    int i = tid / HF, j = tid - i * HF;
    int ri = (i * HH) / HF, ci = (j * WW) / HF;
    float v = (mb[ri * WW + ci] != 0) ? 1.f : 0.f;
    msbuf[(size_t)bk * NN + tid] = v;

    float s = v;
    for (int off = 32; off > 0; off >>= 1) s += __shfl_down(s, off);
    __shared__ float rsum[9];
    if ((tid & 63) == 0) rsum[tid >> 6] = s;
    __syncthreads();
    if (tid == 0) {
        float t = 0.f;
        for (int q = 0; q < 9; ++q) t += rsum[q];
        invbuf[bk] = 1.0f / fmaxf(t, 1e-6f);
    }
}

// ---------------- K1: fused, block-role-specialized, 2:1 stream:pool --------
// A/B vs R9: mask stream uses PLAIN CACHED loads (NT removed). Pool reads fm
// exactly once (no L2-residency dependence), so NT's protective role is gone;
// testing whether the NT/L2-bypass path was capping read BW at ~5 TB/s.
__global__ __launch_bounds__(512, 4) void k_fused(const int* __restrict__ masks,
                                                  const float* __restrict__ fm,
                                                  const float* __restrict__ msbuf,
                                                  const float* __restrict__ invbuf,
                                                  float* __restrict__ xbuf) {
    const int bid = blockIdx.x;        // 0..767
    const int tid = threadIdx.x;       // 512
    const int trio = bid / 3;
    const int rem = bid - trio * 3;

    // union of both roles' LDS (per-kernel static allocation)
    __shared__ float fmT[2][32][68];   // 17.4 KB
    __shared__ float mskS[2][64][68];  // 34.8 KB
    __shared__ float fredL[64][32];    // 8 KB
    __shared__ float pacc[256][12];    // 12 KB
    __shared__ float fmean_s[32];
    __shared__ int r0[8], r1[8], r2[8], r3[8], r4[8], r5[8], r6[8];

    if (rem < 2) {
        // ===================== GEOM: mask stream + geometry ================
        const int bk = trio * 2 + rem;       // 0..511
        const iv4* mp = (const iv4*)(masks + (size_t)bk * (HH * WW));
        const int y0 = tid >> 7;             // row offset within 4-row stripe
        const int xb = (tid & 127) << 2;     // loop-invariant column base
        int cnt = 0, w3a = 0, syr = 0, colany = 0;
        int ymn_it = 1 << 20, ymx_it = -1;

        #pragma unroll 8
        for (int it = 0; it < 128; ++it) {
            iv4 m = mp[tid + (it << 9)];     // cached load (NT removed)
            int sum4 = m.x + m.y + m.z + m.w;
            int mask4 = m.x | (m.y << 1) | (m.z << 2) | (m.w << 3);
            cnt += sum4;
            w3a += m.y + (m.z << 1) + ((m.w << 1) + m.w);
            syr += sum4 * it;
            colany |= mask4;
            if (mask4) { ymn_it = min(ymn_it, it); ymx_it = it; }  // monotone
        }

        // per-lane finalize: y = 4*it + y0
        int sx = xb * cnt + w3a;
        int sy = (syr << 2) + y0 * cnt;
        int xmn = colany ? xb + __builtin_ctz((unsigned)colany) : (1 << 30);
        int xmx = colany ? xb + (31 - __builtin_clz((unsigned)colany)) : -1;
        int ymn = (ymx_it >= 0) ? (ymn_it << 2) + y0 : (1 << 30);
        int ymx = (ymx_it >= 0) ? (ymx_it << 2) + y0 : -1;

        for (int off = 32; off > 0; off >>= 1) {
            cnt += __shfl_down(cnt, off);
            sx  += __shfl_down(sx,  off);
            sy  += __shfl_down(sy,  off);
            xmn = min(xmn, __shfl_down(xmn, off));
            xmx = max(xmx, __shfl_down(xmx, off));
            ymn = min(ymn, __shfl_down(ymn, off));
            ymx = max(ymx, __shfl_down(ymx, off));
        }
        int wv = tid >> 6;   // 0..7
        if ((tid & 63) == 0) {
            r0[wv] = cnt; r1[wv] = sx; r2[wv] = sy;
            r3[wv] = xmn; r4[wv] = xmx; r5[wv] = ymn; r6[wv] = ymx;
        }
        __syncthreads();
        if (tid == 0) {
            for (int i = 1; i < 8; ++i) {
                cnt += r0[i]; sx += r1[i]; sy += r2[i];
                xmn = min(xmn, r3[i]); xmx = max(xmx, r4[i]);
                ymn = min(ymn, r5[i]); ymx = max(ymx, r6[i]);
            }
            float* gp = xbuf + (size_t)bk * XSTRIDE + DD;
            if (cnt >= 1) {
                float area = (float)cnt;
                gp[0] = (float)sx / area * (1.0f / 512.0f);
                gp[1] = (float)sy / area * (1.0f / 512.0f);
                gp[2] = area * (1.0f / 262144.0f);
                gp[3] = (float)(xmx - xmn + 1) * (1.0f / 512.0f);
                gp[4] = (float)(ymx - ymn + 1) * (1.0f / 512.0f);
            } else {
                gp[0] = 0.f; gp[1] = 0.f; gp[2] = 0.f; gp[3] = 0.f; gp[4] = 0.f;
            }
            gp[5] = 0.f; gp[6] = 0.f; gp[7] = 0.f;   // pad cols 1029..1031
        }
    } else {
        // ===================== POOL: tiled einsum, fm read once ============
        const int b = bid & 7;               // bijective per earlier analysis
        const int dt = trio >> 3;            // 0..31
        const int d0 = dt << 5;
        const int team = tid >> 8, ttid = tid & 255;
        const int kg = ttid >> 4, dg = ttid & 15;    // 4k x 2d register tile
        const int frow = tid >> 3, fc4 = (tid & 7) << 2;
        const int mk = tid >> 3, mf = tid & 7;

        float acc[4][2] = {{0.f,0.f},{0.f,0.f},{0.f,0.f},{0.f,0.f}};
        float facc4[4] = {0.f, 0.f, 0.f, 0.f};

        const float* fmb = fm + (size_t)b * NN * DD + d0;
        const float* msb = msbuf + (size_t)b * KK * NN;

        for (int r = 0; r < 5; ++r) {
            {   // stage buf0 = chunk r (all 512 threads)
                int n0 = r << 6;
                float4 v = *(const float4*)&fmb[(size_t)(n0 + frow) * DD + fc4];
                facc4[0] += v.x; facc4[1] += v.y; facc4[2] += v.z; facc4[3] += v.w;
                fmT[0][fc4 + 0][frow] = v.x;
                fmT[0][fc4 + 1][frow] = v.y;
                fmT[0][fc4 + 2][frow] = v.z;
                fmT[0][fc4 + 3][frow] = v.w;
                float4 a = *(const float4*)&msb[(size_t)mk * NN + n0 + (mf << 2)];
                float4 c = *(const float4*)&msb[(size_t)mk * NN + n0 + ((mf + 8) << 2)];
                *(float4*)&mskS[0][mk][(mf << 2)] = a;
                *(float4*)&mskS[0][mk][((mf + 8) << 2)] = c;
            }
            if (r < 4) {  // stage buf1 = chunk 5+r
                int n0 = (5 + r) << 6;
                float4 v = *(const float4*)&fmb[(size_t)(n0 + frow) * DD + fc4];
                facc4[0] += v.x; facc4[1] += v.y; facc4[2] += v.z; facc4[3] += v.w;
                fmT[1][fc4 + 0][frow] = v.x;
                fmT[1][fc4 + 1][frow] = v.y;
                fmT[1][fc4 + 2][frow] = v.z;
                fmT[1][fc4 + 3][frow] = v.w;
                float4 a = *(const float4*)&msb[(size_t)mk * NN + n0 + (mf << 2)];
                float4 c = *(const float4*)&msb[(size_t)mk * NN + n0 + ((mf + 8) << 2)];
                *(float4*)&mskS[1][mk][(mf << 2)] = a;
                *(float4*)&mskS[1][mk][((mf + 8) << 2)] = c;
            }
            __syncthreads();
            int c = (team == 0) ? r : 5 + r;
            if (c < 9) {
                #pragma unroll 4
                for (int q = 0; q < 16; ++q) {
                    float4 fa = *(const float4*)&fmT[team][dg][q << 2];
                    float4 fb = *(const float4*)&fmT[team][dg + 16][q << 2];
                    #pragma unroll
                    for (int kk = 0; kk < 4; ++kk) {
                        float4 mv = *(const float4*)&mskS[team][(kg << 2) + kk][q << 2];
                        acc[kk][0] += mv.x * fa.x + mv.y * fa.y + mv.z * fa.z + mv.w * fa.w;
                        acc[kk][1] += mv.x * fb.x + mv.y * fb.y + mv.z * fb.z + mv.w * fb.w;
                    }
                }
            }
            __syncthreads();
        }

        // publish partials
        fredL[frow][fc4 + 0] = facc4[0];
        fredL[frow][fc4 + 1] = facc4[1];
        fredL[frow][fc4 + 2] = facc4[2];
        fredL[frow][fc4 + 3] = facc4[3];
        if (team == 1) {
            #pragma unroll
            for (int kk = 0; kk < 4; ++kk) {
                pacc[ttid][kk * 2 + 0] = acc[kk][0];
                pacc[ttid][kk * 2 + 1] = acc[kk][1];
            }
        }
        __syncthreads();
        if (tid < 32) {
            float s = 0.f;
            #pragma unroll
            for (int i = 0; i < 64; ++i) s += fredL[i][tid];
            fmean_s[tid] = s * (1.0f / 576.0f);
        }
        __syncthreads();
        if (team == 0) {
            float fm_a = fmean_s[dg], fm_b = fmean_s[dg + 16];
            #pragma unroll
            for (int kk = 0; kk < 4; ++kk) {
                int k = kg * 4 + kk;
                float inv = invbuf[b * KK + k];
                float* xp = xbuf + (size_t)(b * KK + k) * XSTRIDE + d0;
                xp[dg]      = (acc[kk][0] + pacc[ttid][kk * 2 + 0]) * inv - fm_a;
                xp[dg + 16] = (acc[kk][1] + pacc[ttid][kk * 2 + 1]) * inv - fm_b;
            }
        }
    }
}

// ---------------- K2: MLP, 4 rows/block, 512 thr, 8-way j-split -------------
__global__ __launch_bounds__(512) void k_mlp(const float* __restrict__ xbuf,
                                             const float* __restrict__ w1,
                                             const float* __restrict__ b1,
                                             const float* __restrict__ ln_g,
                                             const float* __restrict__ ln_b,
                                             const float* __restrict__ w2,
                                             const float* __restrict__ b2,
                                             float* __restrict__ out) {
    int row0 = blockIdx.x * 4;     // 128 blocks
    int tid = threadIdx.x;         // 512
    int w = tid >> 6, lane = tid & 63;
    int c4 = lane * 4;
    int col = tid & 255, rhalf = tid >> 8;

    __shared__ float xs[4][XSTRIDE];      // 16.5 KB
    __shared__ float hp[8][4][OUTD];      // 32 KB partials [wave][row][col]
    __shared__ float hs[4][OUTD];         // 4 KB

    // float4 staging (xbuf rows are 16B-aligned: 1032*4 % 16 == 0)
    for (int i = tid; i < 4 * (XSTRIDE / 4); i += 512) {
        int r = i / (XSTRIDE / 4), cq = i % (XSTRIDE / 4);
        *(float4*)&xs[r][cq * 4] =
            *(const float4*)&xbuf[(size_t)(row0 + r) * XSTRIDE + cq * 4];
    }
    __syncthreads();

    // ---- phase A: h = x @ w1, j-range per wave (16B-aligned splits) ----
    float acc[4][4] = {};
    int js = w * 128;
    int je = (w == 7) ? 1029 : js + 128;
    int j = js;
    for (; j + 4 <= je; j += 4) {
        float4 xv0 = *(const float4*)&xs[0][j];
        float4 xv1 = *(const float4*)&xs[1][j];
        float4 xv2 = *(const float4*)&xs[2][j];
        float4 xv3 = *(const float4*)&xs[3][j];
#define STEPA(jj, X0, X1, X2, X3)                                              \
        {                                                                      \
            float4 wv = *(const float4*)&w1[(size_t)(j + jj) * OUTD + c4];     \
            acc[0][0] += X0 * wv.x; acc[0][1] += X0 * wv.y;                    \
            acc[0][2] += X0 * wv.z; acc[0][3] += X0 * wv.w;                    \
            acc[1][0] += X1 * wv.x; acc[1][1] += X1 * wv.y;                    \
            acc[1][2] += X1 * wv.z; acc[1][3] += X1 * wv.w;                    \
            acc[2][0] += X2 * wv.x; acc[2][1] += X2 * wv.y;                    \
            acc[2][2] += X2 * wv.z; acc[2][3] += X2 * wv.w;                    \
            acc[3][0] += X3 * wv.x; acc[3][1] += X3 * wv.y;                    \
            acc[3][2] += X3 * wv.z; acc[3][3] += X3 * wv.w;                    \
        }
        STEPA(0, xv0.x, xv1.x, xv2.x, xv3.x)
        STEPA(1, xv0.y, xv1.y, xv2.y, xv3.y)
        STEPA(2, xv0.z, xv1.z, xv2.z, xv3.z)
        STEPA(3, xv0.w, xv1.w, xv2.w, xv3.w)
    }
    for (; j < je; ++j) {   // tail (wave 7: j = 1028)
        float xv[4] = {xs[0][j], xs[1][j], xs[2][j], xs[3][j]};
        #pragma unroll
        for (int ci = 0; ci < 4; ++ci) {
            float wvv = w1[(size_t)j * OUTD + c4 + ci];
            #pragma unroll
            for (int r = 0; r < 4; ++r) acc[r][ci] += xv[r] * wvv;
        }
    }
    #pragma unroll
    for (int r = 0; r < 4; ++r)
        *(float4*)&hp[w][r][c4] = make_float4(acc[r][0], acc[r][1], acc[r][2], acc[r][3]);
    __syncthreads();

    // ---- reduce partials, GELU, LayerNorm (thread = (rhalf, col)) ----
    float h2[2];
    float b1v = b1[col];
    #pragma unroll
    for (int r2 = 0; r2 < 2; ++r2) {
        int r = rhalf * 2 + r2;
        float sv = b1v;
        #pragma unroll
        for (int ww = 0; ww < 8; ++ww) sv += hp[ww][r][col];
        h2[r2] = 0.5f * sv * (1.0f + erff(sv * 0.70710678118654752f));
    }
    __shared__ float s1[8][2], s2[8][2];
    #pragma unroll
    for (int r2 = 0; r2 < 2; ++r2) {
        float a = h2[r2], qv = h2[r2] * h2[r2];
        for (int off = 32; off > 0; off >>= 1) {
            a += __shfl_down(a, off);
            qv += __shfl_down(qv, off);
        }
        if (lane == 0) { s1[w][r2] = a; s2[w][r2] = qv; }
    }
    __syncthreads();
    __shared__ float mu_[4], rsd_[4];
    if (tid < 4) {
        int rh = tid >> 1, r2 = tid & 1;
        float a = 0.f, qv = 0.f;
        #pragma unroll
        for (int i = 0; i < 4; ++i) {
            a += s1[rh * 4 + i][r2];
            qv += s2[rh * 4 + i][r2];
        }
        float mu = a * (1.0f / 256.0f);
        float var = qv * (1.0f / 256.0f) - mu * mu;
        mu_[tid] = mu;
        rsd_[tid] = rsqrtf(var + 1e-5f);
    }
    __syncthreads();
    float gv = ln_g[col], bv = ln_b[col];
    #pragma unroll
    for (int r2 = 0; r2 < 2; ++r2) {
        int r = rhalf * 2 + r2;
        hs[r][col] = (h2[r2] - mu_[r]) * rsd_[r] * gv + bv;
    }
    __syncthreads();

    // ---- phase B: out = hs @ w2, j-range per wave (32 each) ----
    float a2[4][4] = {};
    int j2 = w * 32;
    for (int g = 0; g < 8; ++g, j2 += 4) {
        float4 h0 = *(const float4*)&hs[0][j2];
        float4 h1 = *(const float4*)&hs[1][j2];
        float4 h2v = *(const float4*)&hs[2][j2];
        float4 h3 = *(const float4*)&hs[3][j2];
#define STEPB(jj, X0, X1, X2, X3)                                              \
        {                                                                      \
            float4 wv = *(const float4*)&w2[(size_t)(j2 + jj) * OUTD + c4];    \
            a2[0][0] += X0 * wv.x; a2[0][1] += X0 * wv.y;                      \
            a2[0][2] += X0 * wv.z; a2[0][3] += X0 * wv.w;                      \
            a2[1][0] += X1 * wv.x; a2[1][1] += X1 * wv.y;                      \
            a2[1][2] += X1 * wv.z; a2[1][3] += X1 * wv.w;                      \
            a2[2][0] += X2 * wv.x; a2[2][1] += X2 * wv.y;                      \
            a2[2][2] += X2 * wv.z; a2[2][3] += X2 * wv.w;                      \
            a2[3][0] += X3 * wv.x; a2[3][1] += X3 * wv.y;                      \
            a2[3][2] += X3 * wv.z; a2[3][3] += X3 * wv.w;                      \
        }
        STEPB(0, h0.x, h1.x, h2v.x, h3.x)
        STEPB(1, h0.y, h1.y, h2v.y, h3.y)
        STEPB(2, h0.z, h1.z, h2v.z, h3.z)
        STEPB(3, h0.w, h1.w, h2v.w, h3.w)
    }
    #pragma unroll
    for (int r = 0; r < 4; ++r)
        *(float4*)&hp[w][r][c4] = make_float4(a2[r][0], a2[r][1], a2[r][2], a2[r][3]);
    __syncthreads();

    float b2v = b2[col];
    #pragma unroll
    for (int r2 = 0; r2 < 2; ++r2) {
        int r = rhalf * 2 + r2;
        float o = b2v;
        #pragma unroll
        for (int ww = 0; ww < 8; ++ww) o += hp[ww][r][col];
        out[(size_t)(row0 + r) * OUTD + col] = o;
    }
}

extern "C" void kernel_launch(void* const* d_in, const int* in_sizes, int n_in,
                              void* d_out, int out_size, void* d_ws, size_t ws_size,
                              hipStream_t stream) {
    const float* fm    = (const float*)d_in[0];
    const int*   masks = (const int*)d_in[1];
    const float* w1    = (const float*)d_in[2];
    const float* b1    = (const float*)d_in[3];
    const float* ln_g  = (const float*)d_in[4];
    const float* ln_b  = (const float*)d_in[5];
    const float* w2    = (const float*)d_in[6];
    const float* b2    = (const float*)d_in[7];
    float* out = (float*)d_out;

    float* msbuf  = (float*)d_ws;                    // 512*576 floats
    float* invbuf = msbuf + 512 * NN;                // 512 floats
    float* xbuf   = invbuf + 512;                    // 512*1032 floats

    k_ms   <<<512, 576, 0, stream>>>(masks, msbuf, invbuf);
    k_fused<<<768, 512, 0, stream>>>(masks, fm, msbuf, invbuf, xbuf);
    k_mlp  <<<128, 512, 0, stream>>>(xbuf, w1, b1, ln_g, ln_b, w2, b2, out);
}

// Round 12
// 124.322 us; speedup vs baseline: 1.1507x; 1.1507x over previous
//
#include <hip/hip_runtime.h>
#include <math.h>

#define BB 8
#define NN 576
#define DD 1024
#define KK 64
#define HH 512
#define WW 512
#define OUTD 256
#define HF 24
#define XSTRIDE 1032   // 1029 padded to 1032 (16B-aligned rows)

typedef int iv4 __attribute__((ext_vector_type(4)));

// ---------------- K1: fused, BLOCK-role-specialized (R8 best + deeper MLP) --
// 1024 blocks x 512 thr. role=(bid>>3)&1 alternates groups of 8.
//   GEOM: NT-stream the (b,k) mask; 2 iv4 loads/thread/iter (more in-flight).
//   POOL: own m_small gather + float4 pooling from XCD-local L2 + fmean.
__global__ __launch_bounds__(512, 4) void k_fused(const int* __restrict__ masks,
                                                  const float* __restrict__ fm,
                                                  float* __restrict__ xbuf) {
    const int bid = blockIdx.x;        // 0..1023
    const int role = (bid >> 3) & 1;
    const int s = bid & 7;             // = XCD under bid%8 round-robin
    const int q = bid >> 4;            // 0..63
    const int b = s, k = q;
    const int bk = b * KK + k;
    const int tid = threadIdx.x;       // 512

    __shared__ __align__(16) float ms[NN];
    __shared__ float pacc[256][8];
    __shared__ float rsum[8];
    __shared__ float s_inv;
    __shared__ int r0[8], r1[8], r2[8], r3[8], r4[8], r5[8], r6[8];

    if (role == 0) {
        // ===================== GEOM =====================
        const iv4* mp = (const iv4*)(masks + (size_t)bk * (HH * WW));
        const int y0 = tid >> 7;             // 0..3 (A-half row offset)
        const int xb = (tid & 127) << 2;     // loop-invariant column base
        int cntA = 0, cntB = 0, w3a = 0, syr = 0, colany = 0;
        int ymnA = 1 << 20, ymxA = -1, ymnB = 1 << 20, ymxB = -1;

        #pragma unroll 4
        for (int it = 0; it < 64; ++it) {
            iv4 ma = __builtin_nontemporal_load(&mp[tid + (it << 10)]);
            iv4 mbv = __builtin_nontemporal_load(&mp[tid + 512 + (it << 10)]);
            int sumA = ma.x + ma.y + ma.z + ma.w;
            int sumB = mbv.x + mbv.y + mbv.z + mbv.w;
            int mkA = ma.x | (ma.y << 1) | (ma.z << 2) | (ma.w << 3);
            int mkB = mbv.x | (mbv.y << 1) | (mbv.z << 2) | (mbv.w << 3);
            cntA += sumA;
            cntB += sumB;
            w3a += ma.y + (ma.z << 1) + ((ma.w << 1) + ma.w)
                 + mbv.y + (mbv.z << 1) + ((mbv.w << 1) + mbv.w);
            syr += (sumA + sumB) * it;
            colany |= mkA | mkB;
            if (mkA) { ymnA = min(ymnA, it); ymxA = it; }   // y = 8*it + y0
            if (mkB) { ymnB = min(ymnB, it); ymxB = it; }   // y = 8*it + y0+4
        }

        // per-lane finalize
        int cnt = cntA + cntB;
        int sx = xb * cnt + w3a;
        int sy = (syr << 3) + y0 * cnt + (cntB << 2);
        int xmn = colany ? xb + __builtin_ctz((unsigned)colany) : (1 << 30);
        int xmx = colany ? xb + (31 - __builtin_clz((unsigned)colany)) : -1;
        int ymnAv = (ymxA >= 0) ? (ymnA << 3) + y0 : (1 << 30);
        int ymxAv = (ymxA >= 0) ? (ymxA << 3) + y0 : -1;
        int ymnBv = (ymxB >= 0) ? (ymnB << 3) + y0 + 4 : (1 << 30);
        int ymxBv = (ymxB >= 0) ? (ymxB << 3) + y0 + 4 : -1;
        int ymn = min(ymnAv, ymnBv);
        int ymx = max(ymxAv, ymxBv);

        for (int off = 32; off > 0; off >>= 1) {
            cnt += __shfl_down(cnt, off);
            sx  += __shfl_down(sx,  off);
            sy  += __shfl_down(sy,  off);
            xmn = min(xmn, __shfl_down(xmn, off));
            xmx = max(xmx, __shfl_down(xmx, off));
            ymn = min(ymn, __shfl_down(ymn, off));
            ymx = max(ymx, __shfl_down(ymx, off));
        }
        int wv = tid >> 6;   // 0..7
        if ((tid & 63) == 0) {
            r0[wv] = cnt; r1[wv] = sx; r2[wv] = sy;
            r3[wv] = xmn; r4[wv] = xmx; r5[wv] = ymn; r6[wv] = ymx;
        }
        __syncthreads();
        if (tid == 0) {
            for (int i = 1; i < 8; ++i) {
                cnt += r0[i]; sx += r1[i]; sy += r2[i];
                xmn = min(xmn, r3[i]); xmx = max(xmx, r4[i]);
                ymn = min(ymn, r5[i]); ymx = max(ymx, r6[i]);
            }
            float* gp = xbuf + (size_t)bk * XSTRIDE + DD;
            if (cnt >= 1) {
                float area = (float)cnt;
                gp[0] = (float)sx / area * (1.0f / 512.0f);
                gp[1] = (float)sy / area * (1.0f / 512.0f);
                gp[2] = area * (1.0f / 262144.0f);
                gp[3] = (float)(xmx - xmn + 1) * (1.0f / 512.0f);
                gp[4] = (float)(ymx - ymn + 1) * (1.0f / 512.0f);
            } else {
                gp[0] = 0.f; gp[1] = 0.f; gp[2] = 0.f; gp[3] = 0.f; gp[4] = 0.f;
            }
            gp[5] = 0.f; gp[6] = 0.f; gp[7] = 0.f;   // pad cols 1029..1031
        }
    } else {
        // ===================== POOL =====================
        const int* mb = masks + (size_t)bk * (HH * WW);

        // gather m_small (576 samples with 512 threads) + msum
        float msv = 0.f;
        {
            int n = tid;
            int i = n / HF, j = n - i * HF;
            int ri = (i * HH) / HF, ci = (j * WW) / HF;
            float v = (mb[ri * WW + ci] != 0) ? 1.f : 0.f;
            ms[n] = v;
            msv += v;
        }
        if (tid < NN - 512) {
            int n = 512 + tid;
            int i = n / HF, j = n - i * HF;
            int ri = (i * HH) / HF, ci = (j * WW) / HF;
            float v = (mb[ri * WW + ci] != 0) ? 1.f : 0.f;
            ms[n] = v;
            msv += v;
        }
        for (int off = 32; off > 0; off >>= 1) msv += __shfl_down(msv, off);
        if ((tid & 63) == 0) rsum[tid >> 6] = msv;
        __syncthreads();
        if (tid == 0) {
            float t = 0.f;
            for (int i = 0; i < 8; ++i) t += rsum[i];
            s_inv = 1.0f / fmaxf(t, 1e-6f);
        }
        __syncthreads();

        // pooled: thread = (f4-col c4i, n-parity par)
        const int c4i = tid & 255;
        const int par = tid >> 8;
        const float4* fp = (const float4*)(fm + (size_t)b * NN * DD) + c4i;
        float4 acc = make_float4(0.f, 0.f, 0.f, 0.f);
        float4 fac = make_float4(0.f, 0.f, 0.f, 0.f);
        #pragma unroll 4
        for (int n = par; n < NN; n += 2) {
            float mn = ms[n];                        // uniform LDS broadcast
            float4 v = fp[(size_t)n * 256];
            fac.x += v.x; fac.y += v.y; fac.z += v.z; fac.w += v.w;
            acc.x = fmaf(mn, v.x, acc.x);
            acc.y = fmaf(mn, v.y, acc.y);
            acc.z = fmaf(mn, v.z, acc.z);
            acc.w = fmaf(mn, v.w, acc.w);
        }
        if (par == 1) {
            pacc[c4i][0] = acc.x; pacc[c4i][1] = acc.y;
            pacc[c4i][2] = acc.z; pacc[c4i][3] = acc.w;
            pacc[c4i][4] = fac.x; pacc[c4i][5] = fac.y;
            pacc[c4i][6] = fac.z; pacc[c4i][7] = fac.w;
        }
        __syncthreads();
        if (par == 0) {
            acc.x += pacc[c4i][0]; acc.y += pacc[c4i][1];
            acc.z += pacc[c4i][2]; acc.w += pacc[c4i][3];
            fac.x += pacc[c4i][4]; fac.y += pacc[c4i][5];
            fac.z += pacc[c4i][6]; fac.w += pacc[c4i][7];
            float inv = s_inv;
            float4 o;
            o.x = acc.x * inv - fac.x * (1.0f / 576.0f);
            o.y = acc.y * inv - fac.y * (1.0f / 576.0f);
            o.z = acc.z * inv - fac.z * (1.0f / 576.0f);
            o.w = acc.w * inv - fac.w * (1.0f / 576.0f);
            *(float4*)&xbuf[(size_t)bk * XSTRIDE + 4 * c4i] = o;
        }
    }
}

// ---------------- K2: MLP, 4 rows/block, 512 thr, 8-way j-split -------------
__global__ __launch_bounds__(512) void k_mlp(const float* __restrict__ xbuf,
                                             const float* __restrict__ w1,
                                             const float* __restrict__ b1,
                                             const float* __restrict__ ln_g,
                                             const float* __restrict__ ln_b,
                                             const float* __restrict__ w2,
                                             const float* __restrict__ b2,
                                             float* __restrict__ out) {
    int row0 = blockIdx.x * 4;     // 128 blocks
    int tid = threadIdx.x;         // 512
    int w = tid >> 6, lane = tid & 63;
    int c4 = lane * 4;
    int col = tid & 255, rhalf = tid >> 8;

    __shared__ float xs[4][XSTRIDE];      // 16.5 KB
    __shared__ float hp[8][4][OUTD];      // 32 KB partials [wave][row][col]
    __shared__ float hs[4][OUTD];         // 4 KB

    // float4 staging (xbuf rows are 16B-aligned: 1032*4 % 16 == 0)
    for (int i = tid; i < 4 * (XSTRIDE / 4); i += 512) {
        int r = i / (XSTRIDE / 4), cq = i % (XSTRIDE / 4);
        *(float4*)&xs[r][cq * 4] =
            *(const float4*)&xbuf[(size_t)(row0 + r) * XSTRIDE + cq * 4];
    }
    __syncthreads();

    // ---- phase A: h = x @ w1, j-range per wave (16B-aligned splits) ----
    float acc[4][4] = {};
    int js = w * 128;
    int je = (w == 7) ? 1029 : js + 128;
    int j = js;
    for (; j + 4 <= je; j += 4) {
        float4 xv0 = *(const float4*)&xs[0][j];
        float4 xv1 = *(const float4*)&xs[1][j];
        float4 xv2 = *(const float4*)&xs[2][j];
        float4 xv3 = *(const float4*)&xs[3][j];
#define STEPA(jj, X0, X1, X2, X3)                                              \
        {                                                                      \
            float4 wv = *(const float4*)&w1[(size_t)(j + jj) * OUTD + c4];     \
            acc[0][0] += X0 * wv.x; acc[0][1] += X0 * wv.y;                    \
            acc[0][2] += X0 * wv.z; acc[0][3] += X0 * wv.w;                    \
            acc[1][0] += X1 * wv.x; acc[1][1] += X1 * wv.y;                    \
            acc[1][2] += X1 * wv.z; acc[1][3] += X1 * wv.w;                    \
            acc[2][0] += X2 * wv.x; acc[2][1] += X2 * wv.y;                    \
            acc[2][2] += X2 * wv.z; acc[2][3] += X2 * wv.w;                    \
            acc[3][0] += X3 * wv.x; acc[3][1] += X3 * wv.y;                    \
            acc[3][2] += X3 * wv.z; acc[3][3] += X3 * wv.w;                    \
        }
        STEPA(0, xv0.x, xv1.x, xv2.x, xv3.x)
        STEPA(1, xv0.y, xv1.y, xv2.y, xv3.y)
        STEPA(2, xv0.z, xv1.z, xv2.z, xv3.z)
        STEPA(3, xv0.w, xv1.w, xv2.w, xv3.w)
    }
    for (; j < je; ++j) {   // tail (wave 7: j = 1028)
        float xv[4] = {xs[0][j], xs[1][j], xs[2][j], xs[3][j]};
        #pragma unroll
        for (int ci = 0; ci < 4; ++ci) {
            float wvv = w1[(size_t)j * OUTD + c4 + ci];
            #pragma unroll
            for (int r = 0; r < 4; ++r) acc[r][ci] += xv[r] * wvv;
        }
    }
    #pragma unroll
    for (int r = 0; r < 4; ++r)
        *(float4*)&hp[w][r][c4] = make_float4(acc[r][0], acc[r][1], acc[r][2], acc[r][3]);
    __syncthreads();

    // ---- reduce partials, GELU, LayerNorm (thread = (rhalf, col)) ----
    float h2[2];
    float b1v = b1[col];
    #pragma unroll
    for (int r2 = 0; r2 < 2; ++r2) {
        int r = rhalf * 2 + r2;
        float sv = b1v;
        #pragma unroll
        for (int ww = 0; ww < 8; ++ww) sv += hp[ww][r][col];
        h2[r2] = 0.5f * sv * (1.0f + erff(sv * 0.70710678118654752f));
    }
    __shared__ float s1[8][2], s2[8][2];
    #pragma unroll
    for (int r2 = 0; r2 < 2; ++r2) {
        float a = h2[r2], qv = h2[r2] * h2[r2];
        for (int off = 32; off > 0; off >>= 1) {
            a += __shfl_down(a, off);
            qv += __shfl_down(qv, off);
        }
        if (lane == 0) { s1[w][r2] = a; s2[w][r2] = qv; }
    }
    __syncthreads();
    __shared__ float mu_[4], rsd_[4];
    if (tid < 4) {
        int rh = tid >> 1, r2 = tid & 1;
        float a = 0.f, qv = 0.f;
        #pragma unroll
        for (int i = 0; i < 4; ++i) {
            a += s1[rh * 4 + i][r2];
            qv += s2[rh * 4 + i][r2];
        }
        float mu = a * (1.0f / 256.0f);
        float var = qv * (1.0f / 256.0f) - mu * mu;
        mu_[tid] = mu;
        rsd_[tid] = rsqrtf(var + 1e-5f);
    }
    __syncthreads();
    float gv = ln_g[col], bv = ln_b[col];
    #pragma unroll
    for (int r2 = 0; r2 < 2; ++r2) {
        int r = rhalf * 2 + r2;
        hs[r][col] = (h2[r2] - mu_[r]) * rsd_[r] * gv + bv;
    }
    __syncthreads();

    // ---- phase B: out = hs @ w2, j-range per wave (32 each) ----
    float a2[4][4] = {};
    int j2 = w * 32;
    for (int g = 0; g < 8; ++g, j2 += 4) {
        float4 h0 = *(const float4*)&hs[0][j2];
        float4 h1 = *(const float4*)&hs[1][j2];
        float4 h2v = *(const float4*)&hs[2][j2];
        float4 h3 = *(const float4*)&hs[3][j2];
#define STEPB(jj, X0, X1, X2, X3)                                              \
        {                                                                      \
            float4 wv = *(const float4*)&w2[(size_t)(j2 + jj) * OUTD + c4];    \
            a2[0][0] += X0 * wv.x; a2[0][1] += X0 * wv.y;                      \
            a2[0][2] += X0 * wv.z; a2[0][3] += X0 * wv.w;                      \
            a2[1][0] += X1 * wv.x; a2[1][1] += X1 * wv.y;                      \
            a2[1][2] += X1 * wv.z; a2[1][3] += X1 * wv.w;                      \
            a2[2][0] += X2 * wv.x; a2[2][1] += X2 * wv.y;                      \
            a2[2][2] += X2 * wv.z; a2[2][3] += X2 * wv.w;                      \
            a2[3][0] += X3 * wv.x; a2[3][1] += X3 * wv.y;                      \
            a2[3][2] += X3 * wv.z; a2[3][3] += X3 * wv.w;                      \
        }
        STEPB(0, h0.x, h1.x, h2v.x, h3.x)
        STEPB(1, h0.y, h1.y, h2v.y, h3.y)
        STEPB(2, h0.z, h1.z, h2v.z, h3.z)
        STEPB(3, h0.w, h1.w, h2v.w, h3.w)
    }
    #pragma unroll
    for (int r = 0; r < 4; ++r)
        *(float4*)&hp[w][r][c4] = make_float4(a2[r][0], a2[r][1], a2[r][2], a2[r][3]);
    __syncthreads();

    float b2v = b2[col];
    #pragma unroll
    for (int r2 = 0; r2 < 2; ++r2) {
        int r = rhalf * 2 + r2;
        float o = b2v;
        #pragma unroll
        for (int ww = 0; ww < 8; ++ww) o += hp[ww][r][col];
        out[(size_t)(row0 + r) * OUTD + col] = o;
    }
}

extern "C" void kernel_launch(void* const* d_in, const int* in_sizes, int n_in,
                              void* d_out, int out_size, void* d_ws, size_t ws_size,
                              hipStream_t stream) {
    const float* fm    = (const float*)d_in[0];
    const int*   masks = (const int*)d_in[1];
    const float* w1    = (const float*)d_in[2];
    const float* b1    = (const float*)d_in[3];
    const float* ln_g  = (const float*)d_in[4];
    const float* ln_b  = (const float*)d_in[5];
    const float* w2    = (const float*)d_in[6];
    const float* b2    = (const float*)d_in[7];
    float* out = (float*)d_out;

    float* xbuf = (float*)d_ws;                  // 512*1032 floats ≈ 2.11 MB

    k_fused<<<1024, 512, 0, stream>>>(masks, fm, xbuf);
    k_mlp  <<<128, 512, 0, stream>>>(xbuf, w1, b1, ln_g, ln_b, w2, b2, out);
}